// Round 6
// baseline (400.598 us; speedup 1.0000x reference)
//
#include <hip/hip_runtime.h>

// GIN 2-layer, N=100000, E=1600000, D=128.
// R6: fused per-layer kernel: wave-gather aggregation -> LDS (MFMA-ready,
// XOR-swizzled) -> GEMM1 -> h in LDS -> GEMM2 -> store. W pre-baked to bf16
// LDS-images by wcvt. CSR via bucket multisplit (R3).

typedef __attribute__((ext_vector_type(8))) short bf16x8;
typedef __attribute__((ext_vector_type(4))) float floatx4;

#define WS_ALIGN(x) (((x) + 255) & ~(size_t)255)
#define NBMAX 400   // max buckets (n <= 102400)
#define BCAP 6144   // per-bucket capacity (mean 4096, sd ~64)

__device__ __forceinline__ unsigned short f2b(float f) {  // RTNE fp32->bf16
  unsigned u = __builtin_bit_cast(unsigned, f);
  u = (u + 0x7FFF + ((u >> 16) & 1)) >> 16;
  return (unsigned short)u;
}
__device__ __forceinline__ float b2f(unsigned u16) {  // low 16 bits = bf16
  return __builtin_bit_cast(float, u16 << 16);
}

// ---------- phase A: multisplit edges into 256-node buckets ----------
__global__ __launch_bounds__(256) void bucket_split(const int* __restrict__ src,
                                                    const int* __restrict__ dst,
                                                    int* __restrict__ bcnt,
                                                    unsigned* __restrict__ barr, int E, int nb) {
  __shared__ int cnt[NBMAX], base[NBMAX], cur[NBMAX];
  int t = threadIdx.x;
  for (int i = t; i < nb; i += 256) { cnt[i] = 0; cur[i] = 0; }
  __syncthreads();
  int e0 = blockIdx.x * 8192;
  int s[32], d[32];
#pragma unroll
  for (int k = 0; k < 32; k++) {
    int e = e0 + k * 256 + t;
    if (e < E) { s[k] = src[e]; d[k] = dst[e]; } else { d[k] = -1; }
  }
#pragma unroll
  for (int k = 0; k < 32; k++)
    if (d[k] >= 0) atomicAdd(&cnt[d[k] >> 8], 1);
  __syncthreads();
  for (int i = t; i < nb; i += 256) base[i] = cnt[i] ? atomicAdd(&bcnt[i], cnt[i]) : 0;
  __syncthreads();
#pragma unroll
  for (int k = 0; k < 32; k++)
    if (d[k] >= 0) {
      int b = d[k] >> 8;
      int r = atomicAdd(&cur[b], 1);
      barr[(size_t)b * BCAP + base[b] + r] = ((unsigned)(d[k] & 255) << 17) | (unsigned)s[k];
    }
}

// ---------- phase B: scan bucket counts ----------
__global__ void bucket_scan(const int* __restrict__ bcnt, int* __restrict__ sbase, int nb,
                            int* __restrict__ rowptr, int n) {
  __shared__ int buf[512];
  int t = threadIdx.x;
  int v = (t < nb) ? bcnt[t] : 0;
  buf[t] = v;
  __syncthreads();
  for (int off = 1; off < 512; off <<= 1) {
    int add = (t >= off) ? buf[t - off] : 0;
    __syncthreads();
    buf[t] += add;
    __syncthreads();
  }
  if (t < nb) sbase[t] = buf[t] - v;  // exclusive
  if (t == nb - 1) { sbase[nb] = buf[t]; rowptr[n] = buf[t]; }
}

// ---------- phase C: per-bucket CSR finalize ----------
__global__ __launch_bounds__(256) void bucket_csr(const unsigned* __restrict__ barr,
                                                  const int* __restrict__ bcnt,
                                                  const int* __restrict__ sbase,
                                                  int* __restrict__ rowptr, int* __restrict__ srt,
                                                  int n) {
  __shared__ int cnt[256], off[256], off2[256];
  int b = blockIdx.x, t = threadIdx.x;
  int cb = bcnt[b];
  int node0 = b * 256;
  int nlocal = min(256, n - node0);
  cnt[t] = 0;
  off2[t] = 0;
  __syncthreads();
  const unsigned* bp = barr + (size_t)b * BCAP;
  for (int i = t; i < cb; i += 256) atomicAdd(&cnt[bp[i] >> 17], 1);
  __syncthreads();
  int v = cnt[t];
  off[t] = v;
  __syncthreads();
  for (int o = 1; o < 256; o <<= 1) {
    int add = (t >= o) ? off[t - o] : 0;
    __syncthreads();
    off[t] += add;
    __syncthreads();
  }
  int excl = off[t] - v;
  int sb = sbase[b];
  if (t < nlocal) rowptr[node0 + t] = sb + excl;
  cnt[t] = excl;
  __syncthreads();
  for (int i = t; i < cb; i += 256) {
    unsigned pk = bp[i];
    int local = pk >> 17;
    int r = atomicAdd(&off2[local], 1);
    srt[sb + cnt[local] + r] = pk & 0x1FFFF;
  }
}

// ---------- fp32 -> bf16 convert (row-major) ----------
__global__ void cvt_kernel(const float* __restrict__ x, unsigned short* __restrict__ xb, int n4) {
  int i = blockIdx.x * blockDim.x + threadIdx.x;
  if (i < n4) {
    float4 v = ((const float4*)x)[i];
    uint2 pk;
    pk.x = (unsigned)f2b(v.x) | ((unsigned)f2b(v.y) << 16);
    pk.y = (unsigned)f2b(v.z) | ((unsigned)f2b(v.w) << 16);
    ((uint2*)xb)[i] = pk;
  }
}

// ---------- weights -> bf16 LDS-image (XOR-swizzled), once ----------
// image chunk addr: nrow*16 + (c ^ (nrow & 15))   [uint4 units]
__global__ void wcvt_kernel(const float* __restrict__ w0, const float* __restrict__ w1,
                            const float* __restrict__ w2, const float* __restrict__ w3,
                            uint4* __restrict__ img) {
  const float* W = (blockIdx.y == 0) ? w0 : (blockIdx.y == 1) ? w1 : (blockIdx.y == 2) ? w2 : w3;
  int idx = blockIdx.x * 256 + threadIdx.x;  // 0..2047
  int nrow = idx >> 4, c = idx & 15;
  float4 a = ((const float4*)W)[idx * 2];
  float4 b = ((const float4*)W)[idx * 2 + 1];
  uint4 pk;
  pk.x = (unsigned)f2b(a.x) | ((unsigned)f2b(a.y) << 16);
  pk.y = (unsigned)f2b(a.z) | ((unsigned)f2b(a.w) << 16);
  pk.z = (unsigned)f2b(b.x) | ((unsigned)f2b(b.y) << 16);
  pk.w = (unsigned)f2b(b.z) | ((unsigned)f2b(b.w) << 16);
  img[(size_t)blockIdx.y * 2048 + nrow * 16 + (c ^ (nrow & 15))] = pk;
}

// ---------- fused layer: agg -> relu(.@Wa^T+ba) @ Wb^T + bb ----------
// block = 512 thr (8 waves) x 128 nodes. Wave w aggregates nodes
// [blk*128+w*16, +16) (lane=(slot s, chunk c), dwordx4 gather = 4 edges/instr,
// shfl slot-reduce) into LDS bufA (XOR-swizzled, MFMA-ready). Then GEMM1
// (A=bufA, Wa=bufW) -> h into bufA, Wb staged into bufW -> GEMM2 -> store.
template <int OUT_BF16>
__global__ __launch_bounds__(512, 4) void layer_kernel(
    const unsigned short* __restrict__ X, const int* __restrict__ rowptr,
    const int* __restrict__ srt, const uint4* __restrict__ WaImg,
    const float* __restrict__ ba, const uint4* __restrict__ WbImg,
    const float* __restrict__ bb, void* __restrict__ Cout, int n) {
  __shared__ __align__(16) char lds[65536];
  char* bufA = lds;          // agg rows, later h
  char* bufW = lds + 32768;  // Wa, later Wb
  int t = threadIdx.x;
  int wave = t >> 6, lane = t & 63;

  // stage Wa (straight 32KB copy; swizzle pre-baked)
#pragma unroll
  for (int r = 0; r < 4; r++) ((uint4*)bufW)[t + r * 512] = WaImg[t + r * 512];

  // ---- gather + aggregate phase ----
  {
    int c = lane & 15, s = lane >> 4;
    int coff = c * 16;
    const char* Xb = (const char*)X;
    int node0 = blockIdx.x * 128 + wave * 16;
    for (int i = 0; i < 16; i++) {
      int node = node0 + i;
      if (node >= n) break;
      float acc[8];
#pragma unroll
      for (int j = 0; j < 8; j++) acc[j] = 0.f;
      if (s == 0) {  // self row, slot 0 only
        uint4 u = *(const uint4*)(Xb + (unsigned)node * 256 + coff);
        acc[0] += b2f(u.x & 0xffff); acc[1] += b2f(u.x >> 16);
        acc[2] += b2f(u.y & 0xffff); acc[3] += b2f(u.y >> 16);
        acc[4] += b2f(u.z & 0xffff); acc[5] += b2f(u.z >> 16);
        acc[6] += b2f(u.w & 0xffff); acc[7] += b2f(u.w >> 16);
      }
      int p0 = rowptr[node], e = rowptr[node + 1];
      int cnt = e - p0;
      int trips = cnt >> 2;
      int idx = p0 + s;
#pragma unroll 2
      for (int it = 0; it < trips; it++, idx += 4) {
        int r = srt[idx];
        uint4 u = *(const uint4*)(Xb + (unsigned)r * 256 + coff);
        acc[0] += b2f(u.x & 0xffff); acc[1] += b2f(u.x >> 16);
        acc[2] += b2f(u.y & 0xffff); acc[3] += b2f(u.y >> 16);
        acc[4] += b2f(u.z & 0xffff); acc[5] += b2f(u.z >> 16);
        acc[6] += b2f(u.w & 0xffff); acc[7] += b2f(u.w >> 16);
      }
      int rem = cnt & 3;
      if (s < rem) {
        int r = srt[p0 + trips * 4 + s];
        uint4 u = *(const uint4*)(Xb + (unsigned)r * 256 + coff);
        acc[0] += b2f(u.x & 0xffff); acc[1] += b2f(u.x >> 16);
        acc[2] += b2f(u.y & 0xffff); acc[3] += b2f(u.y >> 16);
        acc[4] += b2f(u.z & 0xffff); acc[5] += b2f(u.z >> 16);
        acc[6] += b2f(u.w & 0xffff); acc[7] += b2f(u.w >> 16);
      }
#pragma unroll
      for (int j = 0; j < 8; j++) {
        acc[j] += __shfl_xor(acc[j], 16, 64);
        acc[j] += __shfl_xor(acc[j], 32, 64);
      }
      // lane (c,s) holds cols 8c+2s, 8c+2s+1 -> chunk c, byte s*4
      int lr = wave * 16 + i;
      unsigned pk = (unsigned)f2b(acc[2 * s]) | ((unsigned)f2b(acc[2 * s + 1]) << 16);
      *(unsigned*)(bufA + lr * 256 + ((c ^ (lr & 15)) << 4) + s * 4) = pk;
    }
  }
  __syncthreads();

  // ---- GEMM1: h = relu(A @ Wa^T + ba) ----
  int m = lane & 15, q = lane >> 4;
  int rbase = blockIdx.x * 128;
  int lrA = wave * 16 + m;

  bf16x8 af[4];
#pragma unroll
  for (int ks = 0; ks < 4; ks++)
    af[ks] = *(const bf16x8*)(bufA + lrA * 256 + (((ks * 4 + q) ^ m) << 4));

  floatx4 acc[8];
  floatx4 zf = {0.f, 0.f, 0.f, 0.f};
#pragma unroll
  for (int j = 0; j < 8; j++) acc[j] = zf;
#pragma unroll
  for (int ks = 0; ks < 4; ks++) {
#pragma unroll
    for (int j = 0; j < 8; j++) {
      bf16x8 bf = *(const bf16x8*)(bufW + (j * 16 + m) * 256 + (((ks * 4 + q) ^ m) << 4));
      acc[j] = __builtin_amdgcn_mfma_f32_16x16x32_bf16(af[ks], bf, acc[j], 0, 0, 0);
    }
  }
  __syncthreads();  // all waves done reading bufA(A) and bufW(Wa)

  // epilogue 1: h into bufA; stage Wb into bufW
#pragma unroll
  for (int j = 0; j < 8; j++) {
    float bias = ba[j * 16 + m];
#pragma unroll
    for (int reg = 0; reg < 4; reg++) {
      float v = fmaxf(acc[j][reg] + bias, 0.f);
      int lr = wave * 16 + q * 4 + reg;
      int col = j * 16 + m;
      *(unsigned short*)(bufA + lr * 256 + (((col >> 3) ^ (lr & 15)) << 4) + (col & 7) * 2) =
          f2b(v);
    }
  }
#pragma unroll
  for (int r = 0; r < 4; r++) ((uint4*)bufW)[t + r * 512] = WbImg[t + r * 512];
  __syncthreads();

  // ---- GEMM2: C = h @ Wb^T + bb ----
#pragma unroll
  for (int ks = 0; ks < 4; ks++)
    af[ks] = *(const bf16x8*)(bufA + lrA * 256 + (((ks * 4 + q) ^ m) << 4));
#pragma unroll
  for (int j = 0; j < 8; j++) acc[j] = zf;
#pragma unroll
  for (int ks = 0; ks < 4; ks++) {
#pragma unroll
    for (int j = 0; j < 8; j++) {
      bf16x8 bf = *(const bf16x8*)(bufW + (j * 16 + m) * 256 + (((ks * 4 + q) ^ m) << 4));
      acc[j] = __builtin_amdgcn_mfma_f32_16x16x32_bf16(af[ks], bf, acc[j], 0, 0, 0);
    }
  }

#pragma unroll
  for (int j = 0; j < 8; j++) {
    float bias = bb[j * 16 + m];
#pragma unroll
    for (int reg = 0; reg < 4; reg++) {
      int row = rbase + wave * 16 + q * 4 + reg;
      if (row >= n) continue;
      float v = acc[j][reg] + bias;
      int col = j * 16 + m;
      if (OUT_BF16)
        ((unsigned short*)Cout)[(size_t)row * 128 + col] = f2b(v);
      else
        ((float*)Cout)[(size_t)row * 128 + col] = v;
    }
  }
}

extern "C" void kernel_launch(void* const* d_in, const int* in_sizes, int n_in,
                              void* d_out, int out_size, void* d_ws, size_t ws_size,
                              hipStream_t stream) {
  const float* x   = (const float*)d_in[0];
  const int*   ei  = (const int*)d_in[1];
  const float* w0a = (const float*)d_in[2];
  const float* b0a = (const float*)d_in[3];
  const float* w0b = (const float*)d_in[4];
  const float* b0b = (const float*)d_in[5];
  const float* w1a = (const float*)d_in[6];
  const float* b1a = (const float*)d_in[7];
  const float* w1b = (const float*)d_in[8];
  const float* b1b = (const float*)d_in[9];
  float* out = (float*)d_out;

  int n = in_sizes[0] / 128;  // 100000
  int E = in_sizes[1] / 2;    // 1600000
  const int* src = ei;
  const int* dst = ei + E;
  int nb = (n + 255) / 256;  // 391

  char* w = (char*)d_ws;
  int* rowptr = (int*)w;           w += WS_ALIGN((size_t)(n + 1) * 4);
  int* sbase = (int*)w;            w += WS_ALIGN((size_t)(NBMAX + 1) * 4);
  int* bcnt = (int*)w;             w += WS_ALIGN((size_t)NBMAX * 4);
  int* srt = (int*)w;              w += WS_ALIGN((size_t)E * 4);
  unsigned short* xb = (unsigned short*)w;  w += WS_ALIGN((size_t)n * 128 * 2);
  uint4* wimg = (uint4*)w;         w += WS_ALIGN((size_t)4 * 32768);
  // barr (nb*BCAP uints, ~9.6MB) overlaps y1: barr is dead before layer 1
  // writes y1.
  unsigned* barr = (unsigned*)w;
  unsigned short* y1 = (unsigned short*)w;

  // ---- weights -> bf16 LDS-images ----
  wcvt_kernel<<<dim3(8, 4), 256, 0, stream>>>(w0a, w0b, w1a, w1b, wimg);

  // ---- CSR build (hierarchical) ----
  hipMemsetAsync(bcnt, 0, (size_t)nb * 4, stream);
  bucket_split<<<(E + 8191) / 8192, 256, 0, stream>>>(src, dst, bcnt, barr, E, nb);
  bucket_scan<<<1, 512, 0, stream>>>(bcnt, sbase, nb, rowptr, n);
  bucket_csr<<<nb, 256, 0, stream>>>(barr, bcnt, sbase, rowptr, srt, n);

  // ---- x -> bf16 ----
  cvt_kernel<<<(n * 32 + 255) / 256, 256, 0, stream>>>(x, xb, n * 32);

  int grid = (n + 127) / 128;
  layer_kernel<1><<<grid, 512, 0, stream>>>(xb, rowptr, srt, wimg, b0a, wimg + 2048, b0b, y1, n);
  layer_kernel<0><<<grid, 512, 0, stream>>>(y1, rowptr, srt, wimg + 4096, b1a, wimg + 6144, b1b,
                                            out, n);
}